// Round 16
// baseline (765.396 us; speedup 1.0000x reference)
//
#include <hip/hip_runtime.h>
#include <cstdint>
#include <cstddef>

// NeuralMemory — bf16 MFMA GEMMs, BK=64, swizzled linear LDS.
// R16: R15 + WAVES template. N=512 K=2048 GEMMs use 2-wave 64x128 tiles
//      (each wave still 64x64 = 16 MFMA/step -> ILP preserved, unlike R13's
//      failed 1x4 split), 512 blocks, 48KB LDS -> 3 blocks/CU.
//      N>=1536 and TN GEMMs unchanged (4-wave 128x128).

#define NROWS 8192
#define HDIM  512
#define HEDIM 2048
#define NCHUNK 8
#define BK    64
#define DPCOEF (2.0f / (HDIM * NCHUNK))

typedef unsigned short u16;
typedef __attribute__((ext_vector_type(8))) unsigned short u16x8;
typedef __attribute__((ext_vector_type(8))) short bf16x8;
typedef __attribute__((ext_vector_type(4))) float f32x4;

__device__ __forceinline__ float sigmoidf_(float x){ return 1.0f/(1.0f+__expf(-x)); }
__device__ __forceinline__ float siluf_(float x){ return x*sigmoidf_(x); }
__device__ __forceinline__ float dsiluf_(float x){ float s=sigmoidf_(x); return s*(1.0f+x*(1.0f-s)); }
__device__ __forceinline__ u16 bf1_(float x){
    union{float f; unsigned u;} v; v.f = x;
    return (u16)((v.u + 0x7fffu + ((v.u>>16)&1u)) >> 16);
}
__device__ __forceinline__ unsigned bfpack_(float a, float b){
    union{float f; unsigned u;} ua, ub; ua.f = a; ub.f = b;
    unsigned ra = (ua.u + 0x7fffu + ((ua.u>>16)&1u)) >> 16;
    unsigned rb = (ub.u + 0x7fffu + ((ub.u>>16)&1u)) & 0xffff0000u;
    return ra | rb;
}
__device__ __forceinline__ float bf2f_(u16 h){
    union{unsigned u; float f;} v; v.u = ((unsigned)h) << 16; return v.f;
}
__device__ __forceinline__ int swkey_(int row){
    return (((row>>3)&1)<<2) | (((row>>4)&1)<<1) | ((row>>5)&1);
}
__device__ __forceinline__ void gl_lds16(const u16* g, u16* l){
    __builtin_amdgcn_global_load_lds(
        (const __attribute__((address_space(1))) unsigned*)g,
        (__attribute__((address_space(3))) unsigned*)l, 16, 0, 0);
}
__device__ __forceinline__ void bar_(){ asm volatile("s_barrier" ::: "memory"); }
#define VMCNT12 asm volatile("s_waitcnt vmcnt(12)" ::: "memory")
#define VMCNT8  asm volatile("s_waitcnt vmcnt(8)" ::: "memory")
#define VMCNT0  asm volatile("s_waitcnt vmcnt(0)" ::: "memory")
#define LGKM0   asm volatile("s_waitcnt lgkmcnt(0)" ::: "memory")

// ---------------------------------------------------------------------------
// bf16 GEMM, MTx128 tile (MT = WAVES==4 ? 128 : 64), BK=64, XCD swizzle.
// Each wave computes a 64x64 sub-tile (acc[4][4], 16 MFMA/K-step) always.
// ATR=false: A[M,K], B[N,K] — double-buffered global_load_lds, counted vmcnt.
// ATR=true : A[K,M], B[K,N] — T14 reg-prefetch (WAVES=4 only).
// MODE: 1 h,dsilu | 2 h only | 3 splitK16 pair-packed u32 bf16 partials
//       4 dh=acc*dsilu(aux)->bf | 5 g1=acc+bf(resB)->bf | 6 +b+resF->f32+bf
//       7 +b+resF->f32 | 8 dpred bf16 (aux=v bf16,ldv) | 9 +b+resB->bf
//       10 bf16 out=acc+b (kvq)
// bf16 outputs: LDS-staged coalesced stores. CSUM -> cpart[m0/MT][n0+col].
// ---------------------------------------------------------------------------
template<int MODE, bool ATR, bool CSUM, int WAVES>
__global__ __launch_bounds__(WAVES*64)
void mgemm_k(const u16* __restrict__ A, const u16* __restrict__ B,
             const float* __restrict__ bias, const float* __restrict__ resF,
             const u16* __restrict__ resB, const u16* __restrict__ aux,
             const float* __restrict__ lrs,
             float* __restrict__ outF, u16* __restrict__ outB, u16* __restrict__ outB2,
             float* __restrict__ cpart,
             int M, int N, int K, int lda, int ldb, int ldv)
{
    constexpr int NBUF = ATR ? 1 : 2;
    constexpr int MT   = (WAVES == 4) ? 128 : 64;
    constexpr int NT_  = WAVES * 64;            // threads
    __shared__ __align__(128) u16 As[NBUF][MT*64];
    __shared__ __align__(128) u16 Bs[NBUF][128*64];
    const int tid = threadIdx.x;
    const int lane = tid & 63, wvi = tid >> 6;
    const int wm = (WAVES == 4) ? (wvi >> 1) : 0;
    const int wn = (WAVES == 4) ? (wvi & 1) : wvi;
    constexpr int WNW = (WAVES == 4) ? 2 : 2;   // waves along N (both 2)
    const int lr = lane & 15, lq = lane >> 4;

    const int gx = gridDim.x;
    const int nwg = gx * gridDim.y;
    int bid = blockIdx.y * gx + blockIdx.x;
    bid = (bid & 7) * (nwg >> 3) + (bid >> 3);
    const int m0 = (bid / gx) * MT, n0 = (bid % gx) * 128;

    int kbeg = 0, kend = K;
    if (MODE == 3){ const int ks = K >> 4; kbeg = blockIdx.z * ks; kend = kbeg + ks; }
    const int nk = (kend - kbeg) / BK;

    f32x4 acc[4][4];
    const f32x4 zz = {0.f,0.f,0.f,0.f};
    #pragma unroll
    for (int i = 0; i < 4; ++i)
        #pragma unroll
        for (int j = 0; j < 4; ++j) acc[i][j] = zz;

    // TN staging state (WAVES=4 only)
    const int mc = tid & 15, kp = tid >> 4;
    const int tkey = (((mc&1)<<2)|(((mc>>1)&1)<<1)|((mc>>2)&1));
    const int tcs = ((kp >> 1) ^ tkey) * 8 + (kp & 1) * 4;
    u16x8 rgA0, rgA1, rgA2, rgA3, rgB0, rgB1, rgB2, rgB3;

    auto stageNT = [&](int k0, int b){
        #pragma unroll
        for (int it = 0; it < (MT/8)/WAVES; ++it){
            const int seg = it*WAVES + wvi;
            const int key = (((seg&1)<<2)|(((seg>>1)&1)<<1)|((seg>>2)&1));
            const int row = seg*8 + (lane>>3);
            const int chunk = (lane&7) ^ key;
            gl_lds16(A + (size_t)(m0+row)*lda + k0 + chunk*8, &As[b][seg*512]);
        }
        #pragma unroll
        for (int it = 0; it < 16/WAVES; ++it){
            const int seg = it*WAVES + wvi;
            const int key = (((seg&1)<<2)|(((seg>>1)&1)<<1)|((seg>>2)&1));
            const int row = seg*8 + (lane>>3);
            const int chunk = (lane&7) ^ key;
            gl_lds16(B + (size_t)(n0+row)*ldb + k0 + chunk*8, &Bs[b][seg*512]);
        }
    };
    auto gloadTN = [&](int k0){
        const u16* pa = A + (size_t)(k0 + 4*kp) * lda + m0 + mc*8;
        rgA0 = *(const u16x8*)pa;          rgA1 = *(const u16x8*)(pa + lda);
        rgA2 = *(const u16x8*)(pa+2*lda);  rgA3 = *(const u16x8*)(pa + 3*lda);
        const u16* pb = B + (size_t)(k0 + 4*kp) * ldb + n0 + mc*8;
        rgB0 = *(const u16x8*)pb;          rgB1 = *(const u16x8*)(pb + ldb);
        rgB2 = *(const u16x8*)(pb+2*ldb);  rgB3 = *(const u16x8*)(pb + 3*ldb);
    };
    auto dswriteTN = [&](){
        #pragma unroll
        for (int j = 0; j < 8; ++j){
            uint2 w;
            w.x = (unsigned)rgA0[j] | ((unsigned)rgA1[j] << 16);
            w.y = (unsigned)rgA2[j] | ((unsigned)rgA3[j] << 16);
            *(uint2*)&As[0][(mc*8 + j)*64 + tcs] = w;
            uint2 v;
            v.x = (unsigned)rgB0[j] | ((unsigned)rgB1[j] << 16);
            v.y = (unsigned)rgB2[j] | ((unsigned)rgB3[j] << 16);
            *(uint2*)&Bs[0][(mc*8 + j)*64 + tcs] = v;
        }
    };
    auto mfmaStep = [&](int b){
        #pragma unroll
        for (int ks = 0; ks < 2; ++ks) {
            bf16x8 afr[4], bfr[4];
            #pragma unroll
            for (int i = 0; i < 4; ++i){
                const int ra = wm*64 + i*16 + lr, rb = wn*64 + i*16 + lr;
                afr[i] = *(const bf16x8*)&As[b][ra*64 + (((ks*4 + lq) ^ swkey_(ra)) << 3)];
                bfr[i] = *(const bf16x8*)&Bs[b][rb*64 + (((ks*4 + lq) ^ swkey_(rb)) << 3)];
            }
            #pragma unroll
            for (int mi = 0; mi < 4; ++mi)
                #pragma unroll
                for (int ni = 0; ni < 4; ++ni)
                    acc[mi][ni] = __builtin_amdgcn_mfma_f32_16x16x32_bf16(afr[mi], bfr[ni], acc[mi][ni], 0, 0, 0);
        }
    };

    if (!ATR) {
        stageNT(kbeg, 0);
        int cur = 0;
        for (int i = 0; i < nk; ++i){
            const int k0 = kbeg + i*BK;
            if (i + 1 < nk){
                stageNT(k0 + BK, cur ^ 1);
                if (WAVES == 4) { VMCNT8; } else { VMCNT12; }
            } else { VMCNT0; }
            bar_();
            mfmaStep(cur);
            bar_();
            cur ^= 1;
        }
    } else {
        gloadTN(kbeg);
        dswriteTN();
        LGKM0;
        __syncthreads();
        for (int i = 0; i < nk; ++i){
            const int k0 = kbeg + i*BK;
            const bool hn = (i + 1 < nk);
            if (hn) gloadTN(k0 + BK);
            mfmaStep(0);
            __syncthreads();
            if (hn){ dswriteTN(); LGKM0; }
            __syncthreads();
        }
    }

    if (MODE == 3){
        unsigned* P32 = (unsigned*)outB;
        const size_t zb = (size_t)blockIdx.z * ((size_t)M * N / 2);
        #pragma unroll
        for (int ni = 0; ni < 4; ++ni){
            const int col = n0 + wn*64 + ni*16 + lr;
            #pragma unroll
            for (int mi = 0; mi < 4; ++mi){
                const int pr = (m0 + wm*64 + mi*16 + lq*4) >> 1;
                P32[zb + (size_t)pr*N + col]     = bfpack_(acc[mi][ni][0], acc[mi][ni][1]);
                P32[zb + (size_t)(pr+1)*N + col] = bfpack_(acc[mi][ni][2], acc[mi][ni][3]);
            }
        }
        return;
    }

    if (MODE == 7){
        #pragma unroll
        for (int ni = 0; ni < 4; ++ni){
            const int col = n0 + wn*64 + ni*16 + lr;
            const float bv = bias[col];
            #pragma unroll
            for (int mi = 0; mi < 4; ++mi){
                const int rbase = m0 + wm*64 + mi*16 + lq*4;
                #pragma unroll
                for (int v = 0; v < 4; ++v){
                    const size_t idx = (size_t)(rbase + v) * N + col;
                    outF[idx] = acc[mi][ni][v] + bv + resF[idx];
                }
            }
        }
        return;
    }

    // ---- LDS-staged coalesced bf16 epilogue (single pass; MODE1 uses Bs too)
    u16*  S   = (u16*)&As[0][0];     // MT*128 u16 (= NBUF*MT*64)
    u16*  S2  = (u16*)&Bs[0][0];
    float* red = (float*)&Bs[0][0];
    constexpr int RED = (WAVES == 4) ? 8 : 4;
    float cs[4] = {0.f, 0.f, 0.f, 0.f};
    __syncthreads();
    #pragma unroll
    for (int ni = 0; ni < 4; ++ni){
        const int cl = wn*64 + ni*16 + lr;
        const int col = n0 + cl;
        float bv = 0.0f;
        if (MODE==1 || MODE==2 || MODE==6 || MODE==8 || MODE==9 || MODE==10) bv = bias[col];
        #pragma unroll
        for (int mi = 0; mi < 4; ++mi){
            #pragma unroll
            for (int v = 0; v < 4; ++v){
                const int rl = wm*64 + mi*16 + lq*4 + v;
                const int row = m0 + rl;
                const size_t idx = (size_t)row * N + col;
                const float o = acc[mi][ni][v];
                const int sidx = rl*128 + (cl ^ (((rl>>2)&3)<<4));
                float t;
                if (MODE == 1){
                    const float u = o + bv;
                    t = siluf_(u);
                    S2[sidx] = bf1_(dsiluf_(u));
                }
                else if (MODE == 2){ t = siluf_(o + bv); }
                else if (MODE == 4){ t = o * bf2f_(aux[idx]); if (CSUM) cs[ni] += t; }
                else if (MODE == 5){ t = o + bf2f_(resB[idx]); if (CSUM) cs[ni] += t; }
                else if (MODE == 6){ t = o + bv + resF[idx]; outF[idx] = t; }
                else if (MODE == 8){
                    const float u = o + bv + bf2f_(resB[idx]);
                    t = lrs[row] * DPCOEF * (u - bf2f_(aux[(size_t)row * ldv + col]));
                    if (CSUM) cs[ni] += t;
                }
                else if (MODE == 9){ t = o + bv + bf2f_(resB[idx]); }
                else { t = o + bv; }   // MODE 10
                S[sidx] = bf1_(t);
            }
        }
    }
    if (CSUM){
        #pragma unroll
        for (int ni = 0; ni < 4; ++ni)
            red[(wm*4 + lq)*128 + wn*64 + ni*16 + lr] = cs[ni];
    }
    __syncthreads();
    #pragma unroll
    for (int j = 0; j < 8; ++j){
        const int ix = j*NT_ + tid;
        const int rl = ix >> 4, cc = (ix & 15) << 3;
        *(u16x8*)(outB + (size_t)(m0 + rl) * N + n0 + cc)
            = *(const u16x8*)&S[rl*128 + (cc ^ (((rl>>2)&3)<<4))];
    }
    if (MODE == 1){
        #pragma unroll
        for (int j = 0; j < 8; ++j){
            const int ix = j*NT_ + tid;
            const int rl = ix >> 4, cc = (ix & 15) << 3;
            *(u16x8*)(outB2 + (size_t)(m0 + rl) * N + n0 + cc)
                = *(const u16x8*)&S2[rl*128 + (cc ^ (((rl>>2)&3)<<4))];
        }
    }
    if (CSUM && tid < 128){
        float s = 0.f;
        #pragma unroll
        for (int z = 0; z < RED; ++z) s += red[z*128 + tid];
        cpart[(size_t)(m0 / MT) * N + n0 + tid] = s;
    }
}

// ---------------------------------------------------------------------------
// fused phase-0: elementwise cvts + bias concat + 3 weight transposes
// ---------------------------------------------------------------------------
#define XSLOTS   (NROWS*HDIM/8)
#define W1S      (2*HEDIM*HDIM/8)
#define KVQSLOTS (3*HDIM*HDIM/8)
#define NB_EW    ((XSLOTS + 2*W1S + KVQSLOTS)/256 + 7)
#define TTILE    1024
__global__ __launch_bounds__(256)
void prep_all_k(const float* __restrict__ x,  u16* __restrict__ xb,
                const float* __restrict__ mw1, u16* __restrict__ mw1b,
                const float* __restrict__ mw2, u16* __restrict__ mw2b,
                const float* __restrict__ wk, const float* __restrict__ wv,
                const float* __restrict__ wq, u16* __restrict__ wkvqb,
                const float* __restrict__ bk, const float* __restrict__ bv,
                const float* __restrict__ bq, float* __restrict__ bkvq,
                u16* __restrict__ mw2Tb, u16* __restrict__ mw1T1b)
{
    __shared__ float tile[32][33];
    const int blk = blockIdx.x;
    if (blk >= NB_EW){
        int tj = blk - NB_EW;
        const float* in; u16* outp; int R, C;
        if (tj < TTILE){
            in = mw2; outp = mw2Tb; R = HDIM; C = HEDIM;
        } else if (tj < 2*TTILE){
            in = mw2 + (size_t)HDIM*HEDIM; outp = mw2Tb + (size_t)HEDIM*HDIM;
            R = HDIM; C = HEDIM; tj -= TTILE;
        } else {
            in = mw1 + (size_t)HEDIM*HDIM; outp = mw1T1b;
            R = HEDIM; C = HDIM; tj -= 2*TTILE;
        }
        const int tpc = C/32;
        const int r0 = (tj / tpc) * 32, c0 = (tj % tpc) * 32;
        const int tx = threadIdx.x & 31, ty = threadIdx.x >> 5;
        #pragma unroll
        for (int j = 0; j < 4; ++j)
            tile[ty + 8*j][tx] = in[(size_t)(r0 + ty + 8*j) * C + c0 + tx];
        __syncthreads();
        #pragma unroll
        for (int j = 0; j < 4; ++j)
            outp[(size_t)(c0 + ty + 8*j) * R + r0 + tx] = bf1_(tile[tx][ty + 8*j]);
        return;
    }
    const int id = blk * 256 + threadIdx.x;
    const float* src; u16* dst; int i;
    if (id < XSLOTS){ src = x; dst = xb; i = id; }
    else if (id < XSLOTS + W1S){ src = mw1; dst = mw1b; i = id - XSLOTS; }
    else if (id < XSLOTS + 2*W1S){ src = mw2; dst = mw2b; i = id - XSLOTS - W1S; }
    else if (id < XSLOTS + 2*W1S + KVQSLOTS){
        const int j = id - XSLOTS - 2*W1S;
        const int per = HDIM*HDIM/8;
        src = (j < per) ? wk : (j < 2*per ? wv : wq);
        i = (j < per) ? j : (j < 2*per ? j - per : j - 2*per);
        dst = wkvqb + ((size_t)(j - i)) * 8;
    }
    else {
        const int j = id - XSLOTS - 2*W1S - KVQSLOTS;
        if (j < 3*HDIM)
            bkvq[j] = (j < HDIM) ? bk[j] : (j < 2*HDIM ? bv[j-HDIM] : bq[j-2*HDIM]);
        return;
    }
    const float4 a = *(const float4*)(src + (size_t)i*8);
    const float4 b = *(const float4*)(src + (size_t)i*8 + 4);
    u16x8 o;
    o[0]=bf1_(a.x); o[1]=bf1_(a.y); o[2]=bf1_(a.z); o[3]=bf1_(a.w);
    o[4]=bf1_(b.x); o[5]=bf1_(b.y); o[6]=bf1_(b.z); o[7]=bf1_(b.w);
    *(u16x8*)(dst + (size_t)i*8) = o;
}

template<bool WF32>
__global__ __launch_bounds__(64)
void l2norm_k(const u16* __restrict__ in, int ld,
              float* __restrict__ outF, u16* __restrict__ outB)
{
    const u16* p = in + (size_t)blockIdx.x * ld;
    const int t = threadIdx.x;
    u16x8 v = *(const u16x8*)(p + t*8);
    float f[8];
    #pragma unroll
    for (int j = 0; j < 8; ++j) f[j] = bf2f_(v[j]);
    float s = 0.f;
    #pragma unroll
    for (int j = 0; j < 8; ++j) s += f[j]*f[j];
    #pragma unroll
    for (int o = 1; o < 64; o <<= 1) s += __shfl_xor(s, o);
    const float sc = 1.0f / fmaxf(sqrtf(s), 1e-12f);
    #pragma unroll
    for (int j = 0; j < 8; ++j) f[j] *= sc;
    if (WF32){
        float* q = outF + (size_t)blockIdx.x * HDIM + t*8;
        *(float4*)q     = make_float4(f[0], f[1], f[2], f[3]);
        *(float4*)(q+4) = make_float4(f[4], f[5], f[6], f[7]);
    }
    u16x8 ob;
    #pragma unroll
    for (int j = 0; j < 8; ++j) ob[j] = bf1_(f[j]);
    *(u16x8*)(outB + (size_t)blockIdx.x * HDIM + t*8) = ob;
}

__global__ __launch_bounds__(64)
void gates_k(const float* __restrict__ x,
             const float* __restrict__ wlr, const float* __restrict__ blr,
             const float* __restrict__ wf,  const float* __restrict__ bfp,
             const float* __restrict__ wm,  const float* __restrict__ bm,
             float* __restrict__ lr_s, float* __restrict__ f_s, float* __restrict__ m_s)
{
    const size_t row = blockIdx.x;
    const float* p = x + row * HDIM;
    const int t = threadIdx.x;
    float s0 = 0.f, s1 = 0.f, s2 = 0.f;
    #pragma unroll
    for (int i = 0; i < 8; i += 4){
        float4 xv = *(const float4*)(p   + t*8 + i);
        float4 a  = *(const float4*)(wlr + t*8 + i);
        float4 b  = *(const float4*)(wf  + t*8 + i);
        float4 c  = *(const float4*)(wm  + t*8 + i);
        s0 += xv.x*a.x + xv.y*a.y + xv.z*a.z + xv.w*a.w;
        s1 += xv.x*b.x + xv.y*b.y + xv.z*b.z + xv.w*b.w;
        s2 += xv.x*c.x + xv.y*c.y + xv.z*c.z + xv.w*c.w;
    }
    #pragma unroll
    for (int o = 1; o < 64; o <<= 1){
        s0 += __shfl_xor(s0, o); s1 += __shfl_xor(s1, o); s2 += __shfl_xor(s2, o);
    }
    if (t == 0){
        lr_s[row] = sigmoidf_(s0 + blr[0]) * 0.1f;
        f_s[row]  = sigmoidf_(s1 + bfp[0]);
        m_s[row]  = sigmoidf_(s2 + bm[0]);
    }
}

__global__ __launch_bounds__(256)
void scalars_k(const float* __restrict__ lr_s, const float* __restrict__ f_s,
               const float* __restrict__ m_s, float* __restrict__ sc)
{
    __shared__ float sh0[256], sh1[256], sh2[256];
    const int t = threadIdx.x;
    float s0 = 0.f, s1 = 0.f, s2 = 0.f;
    for (int i = t; i < NROWS; i += 256){ s0 += f_s[i]; s1 += lr_s[i]; s2 += m_s[i]; }
    sh0[t] = s0; sh1[t] = s1; sh2[t] = s2;
    __syncthreads();
    for (int o = 128; o > 0; o >>= 1){
        if (t < o){ sh0[t] += sh0[t+o]; sh1[t] += sh1[t+o]; sh2[t] += sh2[t+o]; }
        __syncthreads();
    }
    if (t == 0){
        sc[0] = sh0[0] / (float)NROWS;
        sc[1] = sh1[0] / (float)NROWS;
        sc[2] = sh2[0] / (float)NROWS;
    }
}

__global__ __launch_bounds__(256)
void colsum_upd_k(const float* __restrict__ part, const float* __restrict__ p,
                  const float* __restrict__ mom, const float* __restrict__ sc,
                  float* __restrict__ nb, int cols, int nparts)
{
    const int c = blockIdx.x * 256 + threadIdx.x;
    if (c < cols){
        float s = 0.f;
        for (int r = 0; r < nparts; ++r) s += part[(size_t)r * cols + c];
        nb[c] = p[c] * (1.0f - sc[0]) + sc[2] * mom[c] - sc[1] * s;
    }
}

__global__ __launch_bounds__(256)
void fupdate16p_k(const float* __restrict__ p, const unsigned* __restrict__ P32,
                  const float* __restrict__ mom, const float* __restrict__ sc,
                  u16* __restrict__ nWb, int N, int MN2)
{
    const int i = blockIdx.x * 256 + threadIdx.x;
    if (i < MN2){
        float g0 = 0.f, g1 = 0.f;
        #pragma unroll
        for (int z = 0; z < 16; ++z){
            const unsigned w = P32[(size_t)z * MN2 + i];
            g0 += bf2f_((u16)(w & 0xffffu));
            g1 += bf2f_((u16)(w >> 16));
        }
        const int c = i & (N - 1);
        const size_t r0 = ((size_t)(i / N) * 2) * N + c;
        nWb[r0]     = bf1_(p[r0]     * (1.0f - sc[0]) + sc[2] * mom[r0]     - sc[1] * g0);
        nWb[r0 + N] = bf1_(p[r0 + N] * (1.0f - sc[0]) + sc[2] * mom[r0 + N] - sc[1] * g1);
    }
}

extern "C" void kernel_launch(void* const* d_in, const int* in_sizes, int n_in,
                              void* d_out, int out_size, void* d_ws, size_t ws_size,
                              hipStream_t stream)
{
    const float* x      = (const float*)d_in[0];
    const float* wq     = (const float*)d_in[1];
    const float* bq     = (const float*)d_in[2];
    const float* wk     = (const float*)d_in[3];
    const float* bk     = (const float*)d_in[4];
    const float* wv     = (const float*)d_in[5];
    const float* bv     = (const float*)d_in[6];
    const float* wlr    = (const float*)d_in[7];
    const float* blr    = (const float*)d_in[8];
    const float* wf     = (const float*)d_in[9];
    const float* bfp    = (const float*)d_in[10];
    const float* wm     = (const float*)d_in[11];
    const float* bm     = (const float*)d_in[12];
    const float* mw1    = (const float*)d_in[13];
    const float* mb1    = (const float*)d_in[14];
    const float* mw2    = (const float*)d_in[15];
    const float* mb2    = (const float*)d_in[16];
    const float* mom_w1 = (const float*)d_in[17];
    const float* mom_b1 = (const float*)d_in[18];
    const float* mom_w2 = (const float*)d_in[19];
    const float* mom_b2 = (const float*)d_in[20];
    float* out = (float*)d_out;

    char* base = (char*)d_ws;
    size_t off = 0;
    auto alloc = [&](size_t bytes)->char*{ char* p = base + off; off += (bytes + 255) & ~(size_t)255; return p; };
    const size_t NHf  = (size_t)NROWS * HDIM  * 4;
    const size_t NHb  = (size_t)NROWS * HDIM  * 2;
    const size_t NHEb = (size_t)NROWS * HEDIM * 2;
    const int    WHALF = HEDIM * HDIM;

    float* F2   = (float*)alloc(NHf);
    u16*  xb    = (u16*) alloc(NHb);
    u16*  kb    = (u16*) alloc(NHb);
    u16*  x1b   = (u16*) alloc(NHb);
    u16*  g2b   = (u16*) alloc(NHb);
    u16*  hb    = (u16*) alloc(NHEb);
    u16*  db    = (u16*) alloc(NHEb);
    u16*  dhb   = (u16*) alloc(NHEb + NHf);
    u16*  wkvqb = (u16*) alloc((size_t)3*HDIM*HDIM*2);
    float* bkvq = (float*)alloc((size_t)3*HDIM*4);
    u16*  mw1b  = (u16*) alloc((size_t)2*WHALF*2);
    u16*  mw2b  = (u16*) alloc((size_t)2*WHALF*2);
    u16*  mw2Tb = (u16*) alloc((size_t)2*WHALF*2);
    u16*  mw1T1b= (u16*) alloc((size_t)WHALF*2);
    u16*  nW1b  = (u16*) alloc((size_t)2*WHALF*2);
    u16*  nW2b  = (u16*) alloc((size_t)2*WHALF*2);
    float* cpart= (float*)alloc((size_t)64*HEDIM*4);
    float* lr_s = (float*)alloc((size_t)NROWS*4);
    float* f_s  = (float*)alloc((size_t)NROWS*4);
    float* m_s  = (float*)alloc((size_t)NROWS*4);
    float* sc   = (float*)alloc(64);
    float* nb1  = (float*)alloc((size_t)2*HEDIM*4);
    float* nb2  = (float*)alloc((size_t)2*HDIM*4);

    u16* qb  = xb;
    u16* g1b = g2b;
    u16* P3b = dhb;
    float* F1 = (float*)((char*)dhb + NHEb);
    unsigned* Pp = (unsigned*)db;

    const dim3 blk(256), blk2(128);
    const dim3 gKVQ  (3*HDIM/128, NROWS/128);
    const dim3 gN512 (HDIM/128,   NROWS/64);     // (4,128) 2-wave tiles
    const dim3 gN2048(HEDIM/128,  NROWS/128);
    const dim3 gTN2  (HEDIM/128, HDIM/128, 16);
    const dim3 gTN1  (HDIM/128,  HEDIM/128, 16);
    const int MN2 = WHALF / 2;

    const float* mw1_1 = mw1 + (size_t)WHALF;
    const float* mw2_1 = mw2 + (size_t)WHALF;

    #define GARG(Ab,Bb,bi,rF,rB,ax,ll,oF,oB,oB2,cp,M,N,K,la,lb,lv) \
        ((const u16*)(Ab),(const u16*)(Bb),(const float*)(bi),(const float*)(rF),\
         (const u16*)(rB),(const u16*)(ax),(const float*)(ll),\
         (float*)(oF),(u16*)(oB),(u16*)(oB2),(float*)(cp),(M),(N),(K),(la),(lb),(lv))

    // ---------- phase 0 ----------
    prep_all_k<<<dim3(NB_EW + 3*TTILE), blk, 0, stream>>>(
        x, xb, mw1, mw1b, mw2, mw2b, wk, wv, wq, wkvqb,
        bk, bv, bq, bkvq, mw2Tb, mw1T1b);
    gates_k<<<NROWS, 64, 0, stream>>>(x, wlr, blr, wf, bfp, wm, bm, lr_s, f_s, m_s);
    scalars_k<<<1, blk, 0, stream>>>(lr_s, f_s, m_s, sc);

    // ---------- phase 1: fused k|v|q projection (bf16 out) ----------
    mgemm_k<10,false,false,4><<<gKVQ, blk, 0, stream>>>GARG(xb, wkvqb, bkvq, 0,0,0,0, 0, P3b, 0, 0, NROWS,3*HDIM,HDIM, HDIM,HDIM, 0);
    l2norm_k<false><<<NROWS, 64, 0, stream>>>(P3b,          3*HDIM, nullptr, kb);
    l2norm_k<true ><<<NROWS, 64, 0, stream>>>(P3b + 2*HDIM, 3*HDIM, F2, qb);

    // ---------- phase 2: memory forward on k ----------
    mgemm_k<2,false,false,4><<<gN2048, blk, 0, stream>>>GARG(kb, mw1b, mb1, 0,0,0,0, 0, hb, 0, 0, NROWS,HEDIM,HDIM, HDIM,HDIM, 0);
    mgemm_k<9,false,false,2><<<gN512, blk2, 0, stream>>>GARG(hb, mw2b, mb2, 0, kb, 0,0, 0, x1b, 0, 0, NROWS,HDIM,HEDIM, HEDIM,HEDIM, 0);
    mgemm_k<1,false,false,4><<<gN2048, blk, 0, stream>>>GARG(x1b, mw1b+WHALF, mb1+HEDIM, 0,0,0,0, 0, hb, db, 0, NROWS,HEDIM,HDIM, HDIM,HDIM, 0);
    mgemm_k<8,false,true,2><<<gN512, blk2, 0, stream>>>GARG(hb, mw2b+WHALF, mb2+HDIM, 0, x1b, P3b + HDIM, lr_s, 0, g2b, 0, cpart, NROWS,HDIM,HEDIM, HEDIM,HEDIM, 3*HDIM);

    // ---------- backward layer 1 ----------
    colsum_upd_k<<<dim3(HDIM/256), blk, 0, stream>>>(cpart, mb2+HDIM, mom_b2+HDIM, sc, nb2+HDIM, HDIM, 128);
    mgemm_k<4,false,true,4><<<gN2048, blk, 0, stream>>>GARG(g2b, mw2Tb+WHALF, 0,0,0, db, 0, 0, dhb, 0, cpart, NROWS,HEDIM,HDIM, HDIM,HDIM, 0);  // dh1 + colsum
    mgemm_k<3,true,false,4><<<gTN2, blk, 0, stream>>>GARG(g2b, hb, 0,0,0,0,0, 0, Pp, 0, 0, HDIM,HEDIM,NROWS, HDIM,HEDIM, 0);                   // gW2_1
    fupdate16p_k<<<dim3((MN2+255)/256), blk, 0, stream>>>(mw2_1, Pp, mom_w2+WHALF, sc, nW2b+WHALF, HEDIM, MN2);
    colsum_upd_k<<<dim3(HEDIM/256), blk, 0, stream>>>(cpart, mb1+HEDIM, mom_b1+HEDIM, sc, nb1+HEDIM, HEDIM, 64);
    mgemm_k<3,true,false,4><<<gTN1, blk, 0, stream>>>GARG(dhb, x1b, 0,0,0,0,0, 0, Pp, 0, 0, HEDIM,HDIM,NROWS, HEDIM,HDIM, 0);                  // gW1_1
    fupdate16p_k<<<dim3((MN2+255)/256), blk, 0, stream>>>(mw1_1, Pp, mom_w1+WHALF, sc, nW1b+WHALF, HDIM, MN2);
    mgemm_k<5,false,true,2><<<gN512, blk2, 0, stream>>>GARG(dhb, mw1T1b, 0, 0, g2b, 0, 0, 0, g1b, 0, cpart, NROWS,HDIM,HEDIM, HEDIM,HEDIM, 0); // g1 + colsum

    // ---------- backward layer 0 (recompute u0 -> hot hb/db) ----------
    colsum_upd_k<<<dim3(HDIM/256), blk, 0, stream>>>(cpart, mb2, mom_b2, sc, nb2, HDIM, 128);
    mgemm_k<1,false,false,4><<<gN2048, blk, 0, stream>>>GARG(kb, mw1b, mb1, 0,0,0,0, 0, hb, db, 0, NROWS,HEDIM,HDIM, HDIM,HDIM, 0);            // u0
    mgemm_k<4,false,true,4><<<gN2048, blk, 0, stream>>>GARG(g1b, mw2Tb, 0,0,0, db, 0, 0, dhb, 0, cpart, NROWS,HEDIM,HDIM, HDIM,HDIM, 0);       // dh0 + colsum
    mgemm_k<3,true,false,4><<<gTN2, blk, 0, stream>>>GARG(g1b, hb, 0,0,0,0,0, 0, Pp, 0, 0, HDIM,HEDIM,NROWS, HDIM,HEDIM, 0);                   // gW2_0
    fupdate16p_k<<<dim3((MN2+255)/256), blk, 0, stream>>>(mw2, Pp, mom_w2, sc, nW2b, HEDIM, MN2);
    colsum_upd_k<<<dim3(HEDIM/256), blk, 0, stream>>>(cpart, mb1, mom_b1, sc, nb1, HEDIM, 64);
    mgemm_k<3,true,false,4><<<gTN1, blk, 0, stream>>>GARG(dhb, kb, 0,0,0,0,0, 0, Pp, 0, 0, HEDIM,HDIM,NROWS, HEDIM,HDIM, 0);                   // gW1_0
    fupdate16p_k<<<dim3((MN2+255)/256), blk, 0, stream>>>(mw1, Pp, mom_w1, sc, nW1b, HDIM, MN2);

    // ---------- phase 4: forward on q with new params ----------
    mgemm_k<2,false,false,4><<<gN2048, blk, 0, stream>>>GARG(qb, nW1b, nb1, 0,0,0,0, 0, hb, 0, 0, NROWS,HEDIM,HDIM, HDIM,HDIM, 0);
    mgemm_k<6,false,false,2><<<gN512, blk2, 0, stream>>>GARG(hb, nW2b, nb2, F2, 0,0,0, F1, x1b, 0, 0, NROWS,HDIM,HEDIM, HEDIM,HEDIM, 0);
    mgemm_k<2,false,false,4><<<gN2048, blk, 0, stream>>>GARG(x1b, nW1b+WHALF, nb1+HEDIM, 0,0,0,0, 0, hb, 0, 0, NROWS,HEDIM,HDIM, HDIM,HDIM, 0);
    mgemm_k<7,false,false,2><<<gN512, blk2, 0, stream>>>GARG(hb, nW2b+WHALF, nb2+HDIM, F1, 0,0,0, out, 0, 0, 0, NROWS,HDIM,HEDIM, HEDIM,HEDIM, 0);

    #undef GARG
    (void)in_sizes; (void)n_in; (void)out_size; (void)ws_size;
}

// Round 17
// 686.701 us; speedup vs baseline: 1.1146x; 1.1146x over previous
//
#include <hip/hip_runtime.h>
#include <cstdint>
#include <cstddef>

// NeuralMemory — bf16 MFMA GEMMs, BK=64, swizzled linear LDS.
// R17 = R15 (measured best, 688.7us): NT = dbuf gl_lds + vmcnt(8); TN = T14
// reg-prefetch; staged coalesced bf16 epilogues (single-pass MODE1); fused
// phase-0; fused kvq; CSUM column sums; split-K16 pair-packed; XCD swizzle.
// R16's 2-wave tiles reverted (occupancy unchanged, B-panel re-reads hurt).

#define NROWS 8192
#define HDIM  512
#define HEDIM 2048
#define NCHUNK 8
#define BK    64
#define DPCOEF (2.0f / (HDIM * NCHUNK))

typedef unsigned short u16;
typedef __attribute__((ext_vector_type(8))) unsigned short u16x8;
typedef __attribute__((ext_vector_type(8))) short bf16x8;
typedef __attribute__((ext_vector_type(4))) float f32x4;

__device__ __forceinline__ float sigmoidf_(float x){ return 1.0f/(1.0f+__expf(-x)); }
__device__ __forceinline__ float siluf_(float x){ return x*sigmoidf_(x); }
__device__ __forceinline__ float dsiluf_(float x){ float s=sigmoidf_(x); return s*(1.0f+x*(1.0f-s)); }
__device__ __forceinline__ u16 bf1_(float x){
    union{float f; unsigned u;} v; v.f = x;
    return (u16)((v.u + 0x7fffu + ((v.u>>16)&1u)) >> 16);
}
__device__ __forceinline__ unsigned bfpack_(float a, float b){
    union{float f; unsigned u;} ua, ub; ua.f = a; ub.f = b;
    unsigned ra = (ua.u + 0x7fffu + ((ua.u>>16)&1u)) >> 16;
    unsigned rb = (ub.u + 0x7fffu + ((ub.u>>16)&1u)) & 0xffff0000u;
    return ra | rb;
}
__device__ __forceinline__ float bf2f_(u16 h){
    union{unsigned u; float f;} v; v.u = ((unsigned)h) << 16; return v.f;
}
__device__ __forceinline__ int swkey_(int row){
    return (((row>>3)&1)<<2) | (((row>>4)&1)<<1) | ((row>>5)&1);
}
__device__ __forceinline__ void gl_lds16(const u16* g, u16* l){
    __builtin_amdgcn_global_load_lds(
        (const __attribute__((address_space(1))) unsigned*)g,
        (__attribute__((address_space(3))) unsigned*)l, 16, 0, 0);
}
__device__ __forceinline__ void bar_(){ asm volatile("s_barrier" ::: "memory"); }
#define VMCNT8  asm volatile("s_waitcnt vmcnt(8)" ::: "memory")
#define VMCNT0  asm volatile("s_waitcnt vmcnt(0)" ::: "memory")
#define LGKM0   asm volatile("s_waitcnt lgkmcnt(0)" ::: "memory")

// ---------------------------------------------------------------------------
// bf16 GEMM, 128x128 tile, BK=64, 4 waves, XCD-chunked block swizzle.
// ATR=false: A[M,K], B[N,K] — double-buffered global_load_lds, vmcnt(8).
// ATR=true : A[K,M], B[K,N] — T14 reg-prefetch, write after read-barrier.
// MODE: 1 h,dsilu | 2 h only | 3 splitK16 pair-packed u32 bf16 partials
//       4 dh=acc*dsilu(aux)->bf | 5 g1=acc+bf(resB)->bf | 6 +b+resF->f32+bf
//       7 +b+resF->f32 | 8 dpred bf16 (aux=v bf16,ldv) | 9 +b+resB->bf
//       10 bf16 out=acc+b (kvq)
// bf16 outputs: LDS-staged coalesced stores (MODE1 single-pass: As=h, Bs=dsilu).
// CSUM: per-block column sums -> cpart[m0/128][n0+col]
// ---------------------------------------------------------------------------
template<int MODE, bool ATR, bool CSUM>
__global__ __launch_bounds__(256)
void mgemm_k(const u16* __restrict__ A, const u16* __restrict__ B,
             const float* __restrict__ bias, const float* __restrict__ resF,
             const u16* __restrict__ resB, const u16* __restrict__ aux,
             const float* __restrict__ lrs,
             float* __restrict__ outF, u16* __restrict__ outB, u16* __restrict__ outB2,
             float* __restrict__ cpart,
             int M, int N, int K, int lda, int ldb, int ldv)
{
    constexpr int NBUF = ATR ? 1 : 2;
    __shared__ __align__(128) u16 As[NBUF][128*64];
    __shared__ __align__(128) u16 Bs[NBUF][128*64];
    const int tid = threadIdx.x;
    const int lane = tid & 63, wvi = tid >> 6;
    const int wm = wvi >> 1, wn = wvi & 1;
    const int lr = lane & 15, lq = lane >> 4;

    const int gx = gridDim.x;
    const int nwg = gx * gridDim.y;
    int bid = blockIdx.y * gx + blockIdx.x;
    bid = (bid & 7) * (nwg >> 3) + (bid >> 3);
    const int m0 = (bid / gx) * 128, n0 = (bid % gx) * 128;

    int kbeg = 0, kend = K;
    if (MODE == 3){ const int ks = K >> 4; kbeg = blockIdx.z * ks; kend = kbeg + ks; }
    const int nk = (kend - kbeg) / BK;

    f32x4 acc[4][4];
    const f32x4 zz = {0.f,0.f,0.f,0.f};
    #pragma unroll
    for (int i = 0; i < 4; ++i)
        #pragma unroll
        for (int j = 0; j < 4; ++j) acc[i][j] = zz;

    // TN staging state
    const int mc = tid & 15, kp = tid >> 4;
    const int tkey = (((mc&1)<<2)|(((mc>>1)&1)<<1)|((mc>>2)&1));
    const int tcs = ((kp >> 1) ^ tkey) * 8 + (kp & 1) * 4;
    u16x8 rgA0, rgA1, rgA2, rgA3, rgB0, rgB1, rgB2, rgB3;

    auto stageNT = [&](int k0, int b){
        #pragma unroll
        for (int it = 0; it < 4; ++it){
            const int seg = it*4 + wvi;
            const int key = (((seg&1)<<2)|(((seg>>1)&1)<<1)|((seg>>2)&1));
            const int row = seg*8 + (lane>>3);
            const int chunk = (lane&7) ^ key;
            gl_lds16(A + (size_t)(m0+row)*lda + k0 + chunk*8, &As[b][seg*512]);
            gl_lds16(B + (size_t)(n0+row)*ldb + k0 + chunk*8, &Bs[b][seg*512]);
        }
    };
    auto gloadTN = [&](int k0){
        const u16* pa = A + (size_t)(k0 + 4*kp) * lda + m0 + mc*8;
        rgA0 = *(const u16x8*)pa;          rgA1 = *(const u16x8*)(pa + lda);
        rgA2 = *(const u16x8*)(pa+2*lda);  rgA3 = *(const u16x8*)(pa + 3*lda);
        const u16* pb = B + (size_t)(k0 + 4*kp) * ldb + n0 + mc*8;
        rgB0 = *(const u16x8*)pb;          rgB1 = *(const u16x8*)(pb + ldb);
        rgB2 = *(const u16x8*)(pb+2*ldb);  rgB3 = *(const u16x8*)(pb + 3*ldb);
    };
    auto dswriteTN = [&](){
        #pragma unroll
        for (int j = 0; j < 8; ++j){
            uint2 w;
            w.x = (unsigned)rgA0[j] | ((unsigned)rgA1[j] << 16);
            w.y = (unsigned)rgA2[j] | ((unsigned)rgA3[j] << 16);
            *(uint2*)&As[0][(mc*8 + j)*64 + tcs] = w;
            uint2 v;
            v.x = (unsigned)rgB0[j] | ((unsigned)rgB1[j] << 16);
            v.y = (unsigned)rgB2[j] | ((unsigned)rgB3[j] << 16);
            *(uint2*)&Bs[0][(mc*8 + j)*64 + tcs] = v;
        }
    };
    auto mfmaStep = [&](int b){
        #pragma unroll
        for (int ks = 0; ks < 2; ++ks) {
            bf16x8 afr[4], bfr[4];
            #pragma unroll
            for (int i = 0; i < 4; ++i){
                const int ra = wm*64 + i*16 + lr, rb = wn*64 + i*16 + lr;
                afr[i] = *(const bf16x8*)&As[b][ra*64 + (((ks*4 + lq) ^ swkey_(ra)) << 3)];
                bfr[i] = *(const bf16x8*)&Bs[b][rb*64 + (((ks*4 + lq) ^ swkey_(rb)) << 3)];
            }
            #pragma unroll
            for (int mi = 0; mi < 4; ++mi)
                #pragma unroll
                for (int ni = 0; ni < 4; ++ni)
                    acc[mi][ni] = __builtin_amdgcn_mfma_f32_16x16x32_bf16(afr[mi], bfr[ni], acc[mi][ni], 0, 0, 0);
        }
    };

    if (!ATR) {
        stageNT(kbeg, 0);
        int cur = 0;
        for (int i = 0; i < nk; ++i){
            const int k0 = kbeg + i*BK;
            if (i + 1 < nk){ stageNT(k0 + BK, cur ^ 1); VMCNT8; }
            else           { VMCNT0; }
            bar_();
            mfmaStep(cur);
            bar_();
            cur ^= 1;
        }
    } else {
        gloadTN(kbeg);
        dswriteTN();
        LGKM0;
        __syncthreads();
        for (int i = 0; i < nk; ++i){
            const int k0 = kbeg + i*BK;
            const bool hn = (i + 1 < nk);
            if (hn) gloadTN(k0 + BK);
            mfmaStep(0);
            __syncthreads();
            if (hn){ dswriteTN(); LGKM0; }
            __syncthreads();
        }
    }

    if (MODE == 3){
        unsigned* P32 = (unsigned*)outB;
        const size_t zb = (size_t)blockIdx.z * ((size_t)M * N / 2);
        #pragma unroll
        for (int ni = 0; ni < 4; ++ni){
            const int col = n0 + wn*64 + ni*16 + lr;
            #pragma unroll
            for (int mi = 0; mi < 4; ++mi){
                const int pr = (m0 + wm*64 + mi*16 + lq*4) >> 1;
                P32[zb + (size_t)pr*N + col]     = bfpack_(acc[mi][ni][0], acc[mi][ni][1]);
                P32[zb + (size_t)(pr+1)*N + col] = bfpack_(acc[mi][ni][2], acc[mi][ni][3]);
            }
        }
        return;
    }

    if (MODE == 7){
        #pragma unroll
        for (int ni = 0; ni < 4; ++ni){
            const int col = n0 + wn*64 + ni*16 + lr;
            const float bv = bias[col];
            #pragma unroll
            for (int mi = 0; mi < 4; ++mi){
                const int rbase = m0 + wm*64 + mi*16 + lq*4;
                #pragma unroll
                for (int v = 0; v < 4; ++v){
                    const size_t idx = (size_t)(rbase + v) * N + col;
                    outF[idx] = acc[mi][ni][v] + bv + resF[idx];
                }
            }
        }
        return;
    }

    // ---- LDS-staged coalesced bf16 epilogue (single pass; MODE1 uses Bs too)
    u16*  S   = (u16*)&As[0][0];
    u16*  S2  = (u16*)&Bs[0][0];
    float* red = (float*)&Bs[0][0];
    float cs[4] = {0.f, 0.f, 0.f, 0.f};
    __syncthreads();
    #pragma unroll
    for (int ni = 0; ni < 4; ++ni){
        const int cl = wn*64 + ni*16 + lr;
        const int col = n0 + cl;
        float bv = 0.0f;
        if (MODE==1 || MODE==2 || MODE==6 || MODE==8 || MODE==9 || MODE==10) bv = bias[col];
        #pragma unroll
        for (int mi = 0; mi < 4; ++mi){
            #pragma unroll
            for (int v = 0; v < 4; ++v){
                const int rl = wm*64 + mi*16 + lq*4 + v;
                const int row = m0 + rl;
                const size_t idx = (size_t)row * N + col;
                const float o = acc[mi][ni][v];
                const int sidx = rl*128 + (cl ^ (((rl>>2)&3)<<4));
                float t;
                if (MODE == 1){
                    const float u = o + bv;
                    t = siluf_(u);
                    S2[sidx] = bf1_(dsiluf_(u));
                }
                else if (MODE == 2){ t = siluf_(o + bv); }
                else if (MODE == 4){ t = o * bf2f_(aux[idx]); if (CSUM) cs[ni] += t; }
                else if (MODE == 5){ t = o + bf2f_(resB[idx]); if (CSUM) cs[ni] += t; }
                else if (MODE == 6){ t = o + bv + resF[idx]; outF[idx] = t; }
                else if (MODE == 8){
                    const float u = o + bv + bf2f_(resB[idx]);
                    t = lrs[row] * DPCOEF * (u - bf2f_(aux[(size_t)row * ldv + col]));
                    if (CSUM) cs[ni] += t;
                }
                else if (MODE == 9){ t = o + bv + bf2f_(resB[idx]); }
                else { t = o + bv; }   // MODE 10
                S[sidx] = bf1_(t);
            }
        }
    }
    if (CSUM){
        #pragma unroll
        for (int ni = 0; ni < 4; ++ni)
            red[(wm*4 + lq)*128 + wn*64 + ni*16 + lr] = cs[ni];
    }
    __syncthreads();
    #pragma unroll
    for (int j = 0; j < 8; ++j){
        const int ix = j*256 + tid;
        const int rl = ix >> 4, cc = (ix & 15) << 3;
        *(u16x8*)(outB + (size_t)(m0 + rl) * N + n0 + cc)
            = *(const u16x8*)&S[rl*128 + (cc ^ (((rl>>2)&3)<<4))];
    }
    if (MODE == 1){
        #pragma unroll
        for (int j = 0; j < 8; ++j){
            const int ix = j*256 + tid;
            const int rl = ix >> 4, cc = (ix & 15) << 3;
            *(u16x8*)(outB2 + (size_t)(m0 + rl) * N + n0 + cc)
                = *(const u16x8*)&S2[rl*128 + (cc ^ (((rl>>2)&3)<<4))];
        }
    }
    if (CSUM && tid < 128){
        float s = 0.f;
        #pragma unroll
        for (int z = 0; z < 8; ++z) s += red[z*128 + tid];
        cpart[(size_t)(m0 >> 7) * N + n0 + tid] = s;
    }
}

// ---------------------------------------------------------------------------
// fused phase-0: elementwise cvts + bias concat + 3 weight transposes
// block ranges: [0, NB_EW) elementwise/bias; [NB_EW, NB_EW+3072) transpose
// ---------------------------------------------------------------------------
#define XSLOTS   (NROWS*HDIM/8)
#define W1S      (2*HEDIM*HDIM/8)
#define KVQSLOTS (3*HDIM*HDIM/8)
#define NB_EW    ((XSLOTS + 2*W1S + KVQSLOTS)/256 + 7)
#define TTILE    1024                    // 32x32 tiles per transpose job
__global__ __launch_bounds__(256)
void prep_all_k(const float* __restrict__ x,  u16* __restrict__ xb,
                const float* __restrict__ mw1, u16* __restrict__ mw1b,
                const float* __restrict__ mw2, u16* __restrict__ mw2b,
                const float* __restrict__ wk, const float* __restrict__ wv,
                const float* __restrict__ wq, u16* __restrict__ wkvqb,
                const float* __restrict__ bk, const float* __restrict__ bv,
                const float* __restrict__ bq, float* __restrict__ bkvq,
                u16* __restrict__ mw2Tb, u16* __restrict__ mw1T1b)
{
    __shared__ float tile[32][33];
    const int blk = blockIdx.x;
    if (blk >= NB_EW){
        // ---- transpose jobs: in [R,C] f32 -> out [C,R] bf16
        int tj = blk - NB_EW;
        const float* in; u16* outp; int R, C;
        if (tj < TTILE){            // mw2 half0: [HDIM, HEDIM] -> [HEDIM, HDIM]
            in = mw2; outp = mw2Tb; R = HDIM; C = HEDIM;
        } else if (tj < 2*TTILE){   // mw2 half1
            in = mw2 + (size_t)HDIM*HEDIM; outp = mw2Tb + (size_t)HEDIM*HDIM;
            R = HDIM; C = HEDIM; tj -= TTILE;
        } else {                    // mw1_1: [HEDIM, HDIM] -> [HDIM, HEDIM]
            in = mw1 + (size_t)HEDIM*HDIM; outp = mw1T1b;
            R = HEDIM; C = HDIM; tj -= 2*TTILE;
        }
        const int tpc = C/32;                   // tiles per row of tiles
        const int r0 = (tj / tpc) * 32, c0 = (tj % tpc) * 32;
        const int tx = threadIdx.x & 31, ty = threadIdx.x >> 5;
        #pragma unroll
        for (int j = 0; j < 4; ++j)
            tile[ty + 8*j][tx] = in[(size_t)(r0 + ty + 8*j) * C + c0 + tx];
        __syncthreads();
        #pragma unroll
        for (int j = 0; j < 4; ++j)
            outp[(size_t)(c0 + ty + 8*j) * R + r0 + tx] = bf1_(tile[tx][ty + 8*j]);
        return;
    }
    const int id = blk * 256 + threadIdx.x;
    const float* src; u16* dst; int i;
    if (id < XSLOTS){ src = x; dst = xb; i = id; }
    else if (id < XSLOTS + W1S){ src = mw1; dst = mw1b; i = id - XSLOTS; }
    else if (id < XSLOTS + 2*W1S){ src = mw2; dst = mw2b; i = id - XSLOTS - W1S; }
    else if (id < XSLOTS + 2*W1S + KVQSLOTS){
        const int j = id - XSLOTS - 2*W1S;
        const int per = HDIM*HDIM/8;
        src = (j < per) ? wk : (j < 2*per ? wv : wq);
        i = (j < per) ? j : (j < 2*per ? j - per : j - 2*per);
        dst = wkvqb + ((size_t)(j - i)) * 8;
    }
    else {
        const int j = id - XSLOTS - 2*W1S - KVQSLOTS;
        if (j < 3*HDIM)
            bkvq[j] = (j < HDIM) ? bk[j] : (j < 2*HDIM ? bv[j-HDIM] : bq[j-2*HDIM]);
        return;
    }
    const float4 a = *(const float4*)(src + (size_t)i*8);
    const float4 b = *(const float4*)(src + (size_t)i*8 + 4);
    u16x8 o;
    o[0]=bf1_(a.x); o[1]=bf1_(a.y); o[2]=bf1_(a.z); o[3]=bf1_(a.w);
    o[4]=bf1_(b.x); o[5]=bf1_(b.y); o[6]=bf1_(b.z); o[7]=bf1_(b.w);
    *(u16x8*)(dst + (size_t)i*8) = o;
}

// row l2norm over HDIM bf16 inputs (row-strided); writes bf16 (+optional f32)
template<bool WF32>
__global__ __launch_bounds__(64)
void l2norm_k(const u16* __restrict__ in, int ld,
              float* __restrict__ outF, u16* __restrict__ outB)
{
    const u16* p = in + (size_t)blockIdx.x * ld;
    const int t = threadIdx.x;
    u16x8 v = *(const u16x8*)(p + t*8);
    float f[8];
    #pragma unroll
    for (int j = 0; j < 8; ++j) f[j] = bf2f_(v[j]);
    float s = 0.f;
    #pragma unroll
    for (int j = 0; j < 8; ++j) s += f[j]*f[j];
    #pragma unroll
    for (int o = 1; o < 64; o <<= 1) s += __shfl_xor(s, o);
    const float sc = 1.0f / fmaxf(sqrtf(s), 1e-12f);
    #pragma unroll
    for (int j = 0; j < 8; ++j) f[j] *= sc;
    if (WF32){
        float* q = outF + (size_t)blockIdx.x * HDIM + t*8;
        *(float4*)q     = make_float4(f[0], f[1], f[2], f[3]);
        *(float4*)(q+4) = make_float4(f[4], f[5], f[6], f[7]);
    }
    u16x8 ob;
    #pragma unroll
    for (int j = 0; j < 8; ++j) ob[j] = bf1_(f[j]);
    *(u16x8*)(outB + (size_t)blockIdx.x * HDIM + t*8) = ob;
}

__global__ __launch_bounds__(64)
void gates_k(const float* __restrict__ x,
             const float* __restrict__ wlr, const float* __restrict__ blr,
             const float* __restrict__ wf,  const float* __restrict__ bfp,
             const float* __restrict__ wm,  const float* __restrict__ bm,
             float* __restrict__ lr_s, float* __restrict__ f_s, float* __restrict__ m_s)
{
    const size_t row = blockIdx.x;
    const float* p = x + row * HDIM;
    const int t = threadIdx.x;
    float s0 = 0.f, s1 = 0.f, s2 = 0.f;
    #pragma unroll
    for (int i = 0; i < 8; i += 4){
        float4 xv = *(const float4*)(p   + t*8 + i);
        float4 a  = *(const float4*)(wlr + t*8 + i);
        float4 b  = *(const float4*)(wf  + t*8 + i);
        float4 c  = *(const float4*)(wm  + t*8 + i);
        s0 += xv.x*a.x + xv.y*a.y + xv.z*a.z + xv.w*a.w;
        s1 += xv.x*b.x + xv.y*b.y + xv.z*b.z + xv.w*b.w;
        s2 += xv.x*c.x + xv.y*c.y + xv.z*c.z + xv.w*c.w;
    }
    #pragma unroll
    for (int o = 1; o < 64; o <<= 1){
        s0 += __shfl_xor(s0, o); s1 += __shfl_xor(s1, o); s2 += __shfl_xor(s2, o);
    }
    if (t == 0){
        lr_s[row] = sigmoidf_(s0 + blr[0]) * 0.1f;
        f_s[row]  = sigmoidf_(s1 + bfp[0]);
        m_s[row]  = sigmoidf_(s2 + bm[0]);
    }
}

__global__ __launch_bounds__(256)
void scalars_k(const float* __restrict__ lr_s, const float* __restrict__ f_s,
               const float* __restrict__ m_s, float* __restrict__ sc)
{
    __shared__ float sh0[256], sh1[256], sh2[256];
    const int t = threadIdx.x;
    float s0 = 0.f, s1 = 0.f, s2 = 0.f;
    for (int i = t; i < NROWS; i += 256){ s0 += f_s[i]; s1 += lr_s[i]; s2 += m_s[i]; }
    sh0[t] = s0; sh1[t] = s1; sh2[t] = s2;
    __syncthreads();
    for (int o = 128; o > 0; o >>= 1){
        if (t < o){ sh0[t] += sh0[t+o]; sh1[t] += sh1[t+o]; sh2[t] += sh2[t+o]; }
        __syncthreads();
    }
    if (t == 0){
        sc[0] = sh0[0] / (float)NROWS;
        sc[1] = sh1[0] / (float)NROWS;
        sc[2] = sh2[0] / (float)NROWS;
    }
}

__global__ __launch_bounds__(256)
void colsum_upd_k(const float* __restrict__ part, const float* __restrict__ p,
                  const float* __restrict__ mom, const float* __restrict__ sc,
                  float* __restrict__ nb, int cols)
{
    const int c = blockIdx.x * 256 + threadIdx.x;
    if (c < cols){
        float s = 0.f;
        for (int r = 0; r < 64; ++r) s += part[(size_t)r * cols + c];
        nb[c] = p[c] * (1.0f - sc[0]) + sc[2] * mom[c] - sc[1] * s;
    }
}

__global__ __launch_bounds__(256)
void fupdate16p_k(const float* __restrict__ p, const unsigned* __restrict__ P32,
                  const float* __restrict__ mom, const float* __restrict__ sc,
                  u16* __restrict__ nWb, int N, int MN2)
{
    const int i = blockIdx.x * 256 + threadIdx.x;
    if (i < MN2){
        float g0 = 0.f, g1 = 0.f;
        #pragma unroll
        for (int z = 0; z < 16; ++z){
            const unsigned w = P32[(size_t)z * MN2 + i];
            g0 += bf2f_((u16)(w & 0xffffu));
            g1 += bf2f_((u16)(w >> 16));
        }
        const int c = i & (N - 1);
        const size_t r0 = ((size_t)(i / N) * 2) * N + c;
        nWb[r0]     = bf1_(p[r0]     * (1.0f - sc[0]) + sc[2] * mom[r0]     - sc[1] * g0);
        nWb[r0 + N] = bf1_(p[r0 + N] * (1.0f - sc[0]) + sc[2] * mom[r0 + N] - sc[1] * g1);
    }
}

extern "C" void kernel_launch(void* const* d_in, const int* in_sizes, int n_in,
                              void* d_out, int out_size, void* d_ws, size_t ws_size,
                              hipStream_t stream)
{
    const float* x      = (const float*)d_in[0];
    const float* wq     = (const float*)d_in[1];
    const float* bq     = (const float*)d_in[2];
    const float* wk     = (const float*)d_in[3];
    const float* bk     = (const float*)d_in[4];
    const float* wv     = (const float*)d_in[5];
    const float* bv     = (const float*)d_in[6];
    const float* wlr    = (const float*)d_in[7];
    const float* blr    = (const float*)d_in[8];
    const float* wf     = (const float*)d_in[9];
    const float* bfp    = (const float*)d_in[10];
    const float* wm     = (const float*)d_in[11];
    const float* bm     = (const float*)d_in[12];
    const float* mw1    = (const float*)d_in[13];
    const float* mb1    = (const float*)d_in[14];
    const float* mw2    = (const float*)d_in[15];
    const float* mb2    = (const float*)d_in[16];
    const float* mom_w1 = (const float*)d_in[17];
    const float* mom_b1 = (const float*)d_in[18];
    const float* mom_w2 = (const float*)d_in[19];
    const float* mom_b2 = (const float*)d_in[20];
    float* out = (float*)d_out;

    char* base = (char*)d_ws;
    size_t off = 0;
    auto alloc = [&](size_t bytes)->char*{ char* p = base + off; off += (bytes + 255) & ~(size_t)255; return p; };
    const size_t NHf  = (size_t)NROWS * HDIM  * 4;
    const size_t NHb  = (size_t)NROWS * HDIM  * 2;
    const size_t NHEb = (size_t)NROWS * HEDIM * 2;
    const int    WHALF = HEDIM * HDIM;

    float* F2   = (float*)alloc(NHf);
    u16*  xb    = (u16*) alloc(NHb);
    u16*  kb    = (u16*) alloc(NHb);
    u16*  x1b   = (u16*) alloc(NHb);
    u16*  g2b   = (u16*) alloc(NHb);
    u16*  hb    = (u16*) alloc(NHEb);
    u16*  db    = (u16*) alloc(NHEb);
    u16*  dhb   = (u16*) alloc(NHEb + NHf);
    u16*  wkvqb = (u16*) alloc((size_t)3*HDIM*HDIM*2);
    float* bkvq = (float*)alloc((size_t)3*HDIM*4);
    u16*  mw1b  = (u16*) alloc((size_t)2*WHALF*2);
    u16*  mw2b  = (u16*) alloc((size_t)2*WHALF*2);
    u16*  mw2Tb = (u16*) alloc((size_t)2*WHALF*2);
    u16*  mw1T1b= (u16*) alloc((size_t)WHALF*2);
    u16*  nW1b  = (u16*) alloc((size_t)2*WHALF*2);
    u16*  nW2b  = (u16*) alloc((size_t)2*WHALF*2);
    float* cpart= (float*)alloc((size_t)64*HEDIM*4);
    float* lr_s = (float*)alloc((size_t)NROWS*4);
    float* f_s  = (float*)alloc((size_t)NROWS*4);
    float* m_s  = (float*)alloc((size_t)NROWS*4);
    float* sc   = (float*)alloc(64);
    float* nb1  = (float*)alloc((size_t)2*HEDIM*4);
    float* nb2  = (float*)alloc((size_t)2*HDIM*4);

    u16* qb  = xb;
    u16* g1b = g2b;
    u16* P3b = dhb;
    float* F1 = (float*)((char*)dhb + NHEb);
    unsigned* Pp = (unsigned*)db;

    const dim3 blk(256);
    const dim3 gKVQ (3*HDIM/128, NROWS/128);
    const dim3 gN512 (HDIM/128,  NROWS/128);
    const dim3 gN2048(HEDIM/128, NROWS/128);
    const dim3 gTN2  (HEDIM/128, HDIM/128, 16);
    const dim3 gTN1  (HDIM/128,  HEDIM/128, 16);
    const int MN2 = WHALF / 2;

    const float* mw1_1 = mw1 + (size_t)WHALF;
    const float* mw2_1 = mw2 + (size_t)WHALF;

    #define GARG(Ab,Bb,bi,rF,rB,ax,ll,oF,oB,oB2,cp,M,N,K,la,lb,lv) \
        ((const u16*)(Ab),(const u16*)(Bb),(const float*)(bi),(const float*)(rF),\
         (const u16*)(rB),(const u16*)(ax),(const float*)(ll),\
         (float*)(oF),(u16*)(oB),(u16*)(oB2),(float*)(cp),(M),(N),(K),(la),(lb),(lv))

    // ---------- phase 0: ONE fused prep kernel + gates + scalars ----------
    prep_all_k<<<dim3(NB_EW + 3*TTILE), blk, 0, stream>>>(
        x, xb, mw1, mw1b, mw2, mw2b, wk, wv, wq, wkvqb,
        bk, bv, bq, bkvq, mw2Tb, mw1T1b);
    gates_k<<<NROWS, 64, 0, stream>>>(x, wlr, blr, wf, bfp, wm, bm, lr_s, f_s, m_s);
    scalars_k<<<1, blk, 0, stream>>>(lr_s, f_s, m_s, sc);

    // ---------- phase 1: fused k|v|q projection (bf16 out) ----------
    mgemm_k<10,false,false><<<gKVQ, blk, 0, stream>>>GARG(xb, wkvqb, bkvq, 0,0,0,0, 0, P3b, 0, 0, NROWS,3*HDIM,HDIM, HDIM,HDIM, 0);
    l2norm_k<false><<<NROWS, 64, 0, stream>>>(P3b,          3*HDIM, nullptr, kb);
    l2norm_k<true ><<<NROWS, 64, 0, stream>>>(P3b + 2*HDIM, 3*HDIM, F2, qb);

    // ---------- phase 2: memory forward on k ----------
    mgemm_k<2,false,false><<<gN2048, blk, 0, stream>>>GARG(kb, mw1b, mb1, 0,0,0,0, 0, hb, 0, 0, NROWS,HEDIM,HDIM, HDIM,HDIM, 0);
    mgemm_k<9,false,false><<<gN512, blk, 0, stream>>>GARG(hb, mw2b, mb2, 0, kb, 0,0, 0, x1b, 0, 0, NROWS,HDIM,HEDIM, HEDIM,HEDIM, 0);
    mgemm_k<1,false,false><<<gN2048, blk, 0, stream>>>GARG(x1b, mw1b+WHALF, mb1+HEDIM, 0,0,0,0, 0, hb, db, 0, NROWS,HEDIM,HDIM, HDIM,HDIM, 0);
    mgemm_k<8,false,true><<<gN512, blk, 0, stream>>>GARG(hb, mw2b+WHALF, mb2+HDIM, 0, x1b, P3b + HDIM, lr_s, 0, g2b, 0, cpart, NROWS,HDIM,HEDIM, HEDIM,HEDIM, 3*HDIM);

    // ---------- backward layer 1 ----------
    colsum_upd_k<<<dim3(HDIM/256), blk, 0, stream>>>(cpart, mb2+HDIM, mom_b2+HDIM, sc, nb2+HDIM, HDIM);
    mgemm_k<4,false,true><<<gN2048, blk, 0, stream>>>GARG(g2b, mw2Tb+WHALF, 0,0,0, db, 0, 0, dhb, 0, cpart, NROWS,HEDIM,HDIM, HDIM,HDIM, 0);  // dh1 + colsum
    mgemm_k<3,true,false><<<gTN2, blk, 0, stream>>>GARG(g2b, hb, 0,0,0,0,0, 0, Pp, 0, 0, HDIM,HEDIM,NROWS, HDIM,HEDIM, 0);                   // gW2_1
    fupdate16p_k<<<dim3((MN2+255)/256), blk, 0, stream>>>(mw2_1, Pp, mom_w2+WHALF, sc, nW2b+WHALF, HEDIM, MN2);
    colsum_upd_k<<<dim3(HEDIM/256), blk, 0, stream>>>(cpart, mb1+HEDIM, mom_b1+HEDIM, sc, nb1+HEDIM, HEDIM);
    mgemm_k<3,true,false><<<gTN1, blk, 0, stream>>>GARG(dhb, x1b, 0,0,0,0,0, 0, Pp, 0, 0, HEDIM,HDIM,NROWS, HEDIM,HDIM, 0);                  // gW1_1
    fupdate16p_k<<<dim3((MN2+255)/256), blk, 0, stream>>>(mw1_1, Pp, mom_w1+WHALF, sc, nW1b+WHALF, HDIM, MN2);
    mgemm_k<5,false,true><<<gN512, blk, 0, stream>>>GARG(dhb, mw1T1b, 0, 0, g2b, 0, 0, 0, g1b, 0, cpart, NROWS,HDIM,HEDIM, HEDIM,HEDIM, 0);  // g1 + colsum

    // ---------- backward layer 0 (recompute u0 -> hot hb/db) ----------
    colsum_upd_k<<<dim3(HDIM/256), blk, 0, stream>>>(cpart, mb2, mom_b2, sc, nb2, HDIM);
    mgemm_k<1,false,false><<<gN2048, blk, 0, stream>>>GARG(kb, mw1b, mb1, 0,0,0,0, 0, hb, db, 0, NROWS,HEDIM,HDIM, HDIM,HDIM, 0);            // u0
    mgemm_k<4,false,true><<<gN2048, blk, 0, stream>>>GARG(g1b, mw2Tb, 0,0,0, db, 0, 0, dhb, 0, cpart, NROWS,HEDIM,HDIM, HDIM,HDIM, 0);       // dh0 + colsum
    mgemm_k<3,true,false><<<gTN2, blk, 0, stream>>>GARG(g1b, hb, 0,0,0,0,0, 0, Pp, 0, 0, HDIM,HEDIM,NROWS, HDIM,HEDIM, 0);                   // gW2_0
    fupdate16p_k<<<dim3((MN2+255)/256), blk, 0, stream>>>(mw2, Pp, mom_w2, sc, nW2b, HEDIM, MN2);
    colsum_upd_k<<<dim3(HEDIM/256), blk, 0, stream>>>(cpart, mb1, mom_b1, sc, nb1, HEDIM);
    mgemm_k<3,true,false><<<gTN1, blk, 0, stream>>>GARG(dhb, kb, 0,0,0,0,0, 0, Pp, 0, 0, HEDIM,HDIM,NROWS, HEDIM,HDIM, 0);                   // gW1_0
    fupdate16p_k<<<dim3((MN2+255)/256), blk, 0, stream>>>(mw1, Pp, mom_w1, sc, nW1b, HDIM, MN2);

    // ---------- phase 4: forward on q with new params ----------
    mgemm_k<2,false,false><<<gN2048, blk, 0, stream>>>GARG(qb, nW1b, nb1, 0,0,0,0, 0, hb, 0, 0, NROWS,HEDIM,HDIM, HDIM,HDIM, 0);
    mgemm_k<6,false,false><<<gN512, blk, 0, stream>>>GARG(hb, nW2b, nb2, F2, 0,0,0, F1, x1b, 0, 0, NROWS,HDIM,HEDIM, HEDIM,HEDIM, 0);
    mgemm_k<2,false,false><<<gN2048, blk, 0, stream>>>GARG(x1b, nW1b+WHALF, nb1+HEDIM, 0,0,0,0, 0, hb, 0, 0, NROWS,HEDIM,HDIM, HDIM,HDIM, 0);
    mgemm_k<7,false,false><<<gN512, blk, 0, stream>>>GARG(hb, nW2b+WHALF, nb2+HDIM, F1, 0,0,0, out, 0, 0, 0, NROWS,HDIM,HEDIM, HEDIM,HEDIM, 0);

    #undef GARG
    (void)in_sizes; (void)n_in; (void)out_size; (void)ws_size;
}